// Round 2
// baseline (361.387 us; speedup 1.0000x reference)
//
#include <hip/hip_runtime.h>

// Dual-key attention, bf16 MFMA pipeline.
// Requires ws_size >= 58 MiB.
//
// ws layout (MiB offsets):
//   0: qbf   [b][h][1024][64] bf16   (8 MiB)
//   8: khat  [b][h][1024][64] bf16   (8)
//  16: vT    [b][h][64][1024] bf16   (8)
//  24: attno [b*1024+n][h*64+d] bf16 (8)
//  32: actA  bf16 activations        (8)
//  40: actB  bf16 activations        (8)
//  48,50,52,54,56: WqT,Wk1T,Wk2T,WvT,WoT bf16 [N][K] (2 each)

typedef short bf16x8 __attribute__((ext_vector_type(8)));
typedef float f32x4 __attribute__((ext_vector_type(4)));

__device__ __forceinline__ unsigned short f2bf(float f) {
  unsigned int u = __float_as_uint(f);
  return (unsigned short)((u + 0x7FFFu + ((u >> 16) & 1u)) >> 16);
}

__device__ __forceinline__ void gload_lds16(const void* g, void* l) {
  __builtin_amdgcn_global_load_lds(
      (const __attribute__((address_space(1))) unsigned int*)g,
      (__attribute__((address_space(3))) unsigned int*)l, 16, 0, 0);
}

// ---------------- fp32 -> bf16 convert ----------------
__global__ __launch_bounds__(256) void conv_bf16_kernel(
    const float* __restrict__ in, unsigned short* __restrict__ out, int n4) {
  int i = blockIdx.x * blockDim.x + threadIdx.x;
  if (i >= n4) return;
  float4 v = ((const float4*)in)[i];
  ushort4 o;
  o.x = f2bf(v.x); o.y = f2bf(v.y); o.z = f2bf(v.z); o.w = f2bf(v.w);
  ((ushort4*)out)[i] = o;
}

// ---------------- W [R][C] fp32 -> W^T [C][R] bf16 ----------------
__global__ __launch_bounds__(256) void transpose_bf16_kernel(
    const float* __restrict__ in, unsigned short* __restrict__ out, int R, int C) {
  __shared__ float tile[32][33];
  const int x = threadIdx.x & 31;
  const int y0 = (threadIdx.x >> 5) << 2;  // 0..28 step 4
  const int r0 = blockIdx.y * 32;
  const int c0 = blockIdx.x * 32;
#pragma unroll
  for (int i = 0; i < 4; ++i)
    tile[y0 + i][x] = in[(size_t)(r0 + y0 + i) * C + c0 + x];
  __syncthreads();
#pragma unroll
  for (int i = 0; i < 4; ++i) {
    int c = y0 + i;
    out[(size_t)(c0 + c) * R + r0 + x] = f2bf(tile[x][c]);
  }
}

// ---------------- bf16 MFMA GEMM: C = A1@B1^T (+ A2@B2^T) + bias ----------------
// A: [M][K] bf16 row-major. B: [N][K] bf16 row-major (i.e. W^T).
// mode 0: bf16 out to [b][h][n][64]   (b=r>>10, n=r&1023, h=c>>6, d=c&63)
// mode 1: bf16 out to [b][h][64][n]   (v transposed)
// mode 2: fp32 out row-major [M][N]
__global__ __launch_bounds__(256) void gemm_kernel(
    const unsigned short* __restrict__ A1, const unsigned short* __restrict__ B1,
    const unsigned short* __restrict__ A2, const unsigned short* __restrict__ B2,
    const float* __restrict__ bias1, const float* __restrict__ bias2,
    void* __restrict__ outp, int M, int N, int K, int mode) {
  __shared__ unsigned short lA[128 * 32];
  __shared__ unsigned short lB[128 * 32];
  const int tid = threadIdx.x;
  const int lane = tid & 63;
  const int wave = tid >> 6;
  const int l15 = lane & 15, lg = lane >> 4;
  const int m0 = blockIdx.x * 128, n0 = blockIdx.y * 128;
  const int wr = wave >> 1, wc = wave & 1;  // 2x2 waves over 128x128, 64x64 each

  f32x4 zero4 = {0.f, 0.f, 0.f, 0.f};
  f32x4 acc[4][4];
#pragma unroll
  for (int i = 0; i < 4; ++i)
#pragma unroll
    for (int j = 0; j < 4; ++j) acc[i][j] = zero4;

  const int npair = (A2 != nullptr) ? 2 : 1;
  for (int pair = 0; pair < npair; ++pair) {
    const unsigned short* A = pair ? A2 : A1;
    const unsigned short* B = pair ? B2 : B1;
    for (int k0 = 0; k0 < K; k0 += 32) {
      __syncthreads();
      // stage 128x32 bf16 tiles (8 KiB each) = 512 chunks x 16B, 2 per thread
#pragma unroll
      for (int rep = 0; rep < 2; ++rep) {
        int c = rep * 256 + tid;
        int row = c >> 2;
        int ko = (c & 3) * 8;
        gload_lds16(&A[(size_t)(m0 + row) * K + k0 + ko],
                    (char*)lA + rep * 4096 + wave * 1024);
        gload_lds16(&B[(size_t)(n0 + row) * K + k0 + ko],
                    (char*)lB + rep * 4096 + wave * 1024);
      }
      __syncthreads();  // drains vmcnt: staged data visible
      bf16x8 af[4], bfr[4];
#pragma unroll
      for (int m = 0; m < 4; ++m)
        af[m] = *(const bf16x8*)&lA[(wr * 64 + m * 16 + l15) * 32 + lg * 8];
#pragma unroll
      for (int n = 0; n < 4; ++n)
        bfr[n] = *(const bf16x8*)&lB[(wc * 64 + n * 16 + l15) * 32 + lg * 8];
#pragma unroll
      for (int m = 0; m < 4; ++m)
#pragma unroll
        for (int n = 0; n < 4; ++n)
          acc[m][n] = __builtin_amdgcn_mfma_f32_16x16x32_bf16(af[m], bfr[n],
                                                              acc[m][n], 0, 0, 0);
    }
  }

  // epilogue: C row = m0+wr*64+m*16+lg*4+j, col = n0+wc*64+n*16+l15
  unsigned short* outb = (unsigned short*)outp;
  float* outf = (float*)outp;
#pragma unroll
  for (int m = 0; m < 4; ++m) {
#pragma unroll
    for (int n = 0; n < 4; ++n) {
      int cg = n0 + wc * 64 + n * 16 + l15;
      float badd = (bias1 ? bias1[cg] : 0.f) + (bias2 ? bias2[cg] : 0.f);
#pragma unroll
      for (int j = 0; j < 4; ++j) {
        int r = m0 + wr * 64 + m * 16 + lg * 4 + j;
        float v = acc[m][n][j] + badd;
        if (mode == 2) {
          outf[(size_t)r * N + cg] = v;
        } else {
          int bb = r >> 10, nn = r & 1023;
          int h = cg >> 6, d = cg & 63;
          if (mode == 0)
            outb[(((size_t)bb * 16 + h) * 1024 + nn) * 64 + d] = f2bf(v);
          else
            outb[(((size_t)bb * 16 + h) * 64 + d) * 1024 + nn] = f2bf(v);
        }
      }
    }
  }
}

// ---------------- fused dual-key attention ----------------
// block = (b, h, 128 q-rows); 4 waves x 32 q-rows each.
// q,kh: [b][h][1024][64] bf16; vT: [b][h][64][1024] bf16;
// aw fp32: [b][h][1024][1024]; msk: same shape, either u8 (jax bool) or i32 —
// detected at runtime from the first 64 words (i32 0/1 words are always <=1;
// random bool bytes packed into words exceed 1 w.p. 1-(1/8)^64).
// out bf16 [b*1024+n][h*64+d].
__global__ __launch_bounds__(256) void attn_kernel(
    const unsigned short* __restrict__ q, const unsigned short* __restrict__ kh,
    const unsigned short* __restrict__ vT, const float* __restrict__ aw,
    const void* __restrict__ msk, unsigned short* __restrict__ attnout) {
  __shared__ unsigned short lK[64 * 64];      // [k][d], rows XOR-swizzled
  __shared__ unsigned short lV[64 * 64];      // [d][k], rows XOR-swizzled
  __shared__ unsigned short lP[4][32 * 64];   // per-wave P tile, swizzled

  const int tid = threadIdx.x, lane = tid & 63, wave = tid >> 6;
  const int l15 = lane & 15, lg = lane >> 4;
  const int qt = blockIdx.x & 7;
  const int bh = blockIdx.x >> 3;
  const int b = bh >> 4, h = bh & 15;
  const int qbase = qt * 128 + wave * 32;  // local q row within (b,h)

  // ---- mask dtype detection (wave-uniform) ----
  unsigned w0 = ((const unsigned*)msk)[lane];
  const bool mbyte = (__ballot(w0 > 1u) != 0ull);
  const unsigned char* mp8 = (const unsigned char*)msk + (size_t)bh * 1048576;
  const int* mpi = (const int*)msk + (size_t)bh * 1048576;

  const unsigned short* qp = q + (size_t)bh * 65536;
  const unsigned short* kp = kh + (size_t)bh * 65536;
  const unsigned short* vp = vT + (size_t)bh * 65536;
  const float* awp = aw + (size_t)bh * 1048576;

  // Q fragments in registers: rows qbase+m*16+l15, d = kk*32+lg*8..+7
  bf16x8 qf[2][2];
#pragma unroll
  for (int m = 0; m < 2; ++m)
#pragma unroll
    for (int kk = 0; kk < 2; ++kk)
      qf[m][kk] = *(const bf16x8*)&qp[(qbase + m * 16 + l15) * 64 + kk * 32 + lg * 8];

  f32x4 zero4 = {0.f, 0.f, 0.f, 0.f};
  f32x4 oacc[2][4];
  float mrun[2][4], lrun[2][4];
#pragma unroll
  for (int m = 0; m < 2; ++m)
#pragma unroll
    for (int x = 0; x < 4; ++x) {
      oacc[m][x] = zero4;
      mrun[m][x] = -1e30f;
      lrun[m][x] = 0.f;
    }

  const float scale = 0.08838834764831845f;  // 1/sqrt(128)

  for (int kt = 0; kt < 16; ++kt) {
    // stage K tile [64][64] and V^T tile [64][64]; source-side XOR swizzle,
    // linear LDS dest (global_load_lds constraint), swizzled reads below.
#pragma unroll
    for (int rep = 0; rep < 2; ++rep) {
      int c = rep * 256 + tid;
      int row = c >> 3;
      int off = ((c & 7) * 16) ^ ((row & 7) << 4);  // byte offset in 128B row
      gload_lds16(&kp[(size_t)(kt * 64 + row) * 64 + (off >> 1)],
                  (char*)lK + rep * 4096 + wave * 1024);
      gload_lds16(&vp[(size_t)row * 1024 + kt * 64 + (off >> 1)],
                  (char*)lV + rep * 4096 + wave * 1024);
    }
    __syncthreads();

    // S = Q @ K^T  (C layout: col=l15=k-index, row=lg*4+j=q-row)
    f32x4 sacc[2][4];
#pragma unroll
    for (int m = 0; m < 2; ++m)
#pragma unroll
      for (int nf = 0; nf < 4; ++nf) sacc[m][nf] = zero4;
#pragma unroll
    for (int kk = 0; kk < 2; ++kk) {
      bf16x8 kf[4];
#pragma unroll
      for (int nf = 0; nf < 4; ++nf) {
        int row = nf * 16 + l15;
        int off = (kk * 64 + lg * 16) ^ ((row & 7) << 4);
        kf[nf] = *(const bf16x8*)((const char*)lK + row * 128 + off);
      }
#pragma unroll
      for (int m = 0; m < 2; ++m)
#pragma unroll
        for (int nf = 0; nf < 4; ++nf)
          sacc[m][nf] = __builtin_amdgcn_mfma_f32_16x16x32_bf16(qf[m][kk], kf[nf],
                                                                sacc[m][nf], 0, 0, 0);
    }

    // scale * aw, mask, online softmax, P -> LDS (bf16)
#pragma unroll
    for (int m = 0; m < 2; ++m) {
      float pvv[4][4];
      float alpha[4];
#pragma unroll
      for (int j = 0; j < 4; ++j) {
        const int r = qbase + m * 16 + lg * 4 + j;
        const float* awrow = awp + (size_t)r * 1024 + kt * 64;
        const size_t mbase = (size_t)r * 1024 + kt * 64;
        int mvv[4];
        if (mbyte) {
#pragma unroll
          for (int nf = 0; nf < 4; ++nf) mvv[nf] = mp8[mbase + nf * 16 + l15];
        } else {
#pragma unroll
          for (int nf = 0; nf < 4; ++nf) mvv[nf] = mpi[mbase + nf * 16 + l15];
        }
        float mx = -1e30f;
#pragma unroll
        for (int nf = 0; nf < 4; ++nf) {
          int c = nf * 16 + l15;
          float s = sacc[m][nf][j] * scale * awrow[c];
          s = mvv[nf] ? -1e30f : s;
          pvv[j][nf] = s;
          mx = fmaxf(mx, s);
        }
        mx = fmaxf(mx, __shfl_xor(mx, 1));
        mx = fmaxf(mx, __shfl_xor(mx, 2));
        mx = fmaxf(mx, __shfl_xor(mx, 4));
        mx = fmaxf(mx, __shfl_xor(mx, 8));
        float mnew = fmaxf(mrun[m][j], mx);
        float al = __expf(mrun[m][j] - mnew);
        mrun[m][j] = mnew;
        float psum = 0.f;
#pragma unroll
        for (int nf = 0; nf < 4; ++nf) {
          float s = pvv[j][nf];
          float p = (s <= -1e29f) ? 0.f : __expf(s - mnew);  // guard all-masked
          pvv[j][nf] = p;
          psum += p;
        }
        psum += __shfl_xor(psum, 1);
        psum += __shfl_xor(psum, 2);
        psum += __shfl_xor(psum, 4);
        psum += __shfl_xor(psum, 8);
        lrun[m][j] = lrun[m][j] * al + psum;
        alpha[j] = al;
      }
#pragma unroll
      for (int df = 0; df < 4; ++df)
#pragma unroll
        for (int j = 0; j < 4; ++j) oacc[m][df][j] *= alpha[j];
      // write P tile: row = m*16+lg*4+j (uniform across l15 lanes), col = nf*16+l15
#pragma unroll
      for (int j = 0; j < 4; ++j) {
        int prow = m * 16 + lg * 4 + j;
#pragma unroll
        for (int nf = 0; nf < 4; ++nf) {
          int pb = ((nf * 16 + l15) * 2) ^ ((prow & 7) << 4);
          *(unsigned short*)((char*)lP[wave] + prow * 128 + pb) = f2bf(pvv[j][nf]);
        }
      }
    }

    // O += P @ V  (A=P from own wave's LDS tile, B=V^T tile)
#pragma unroll
    for (int kk2 = 0; kk2 < 2; ++kk2) {
      bf16x8 vf[4], pf[2];
#pragma unroll
      for (int df = 0; df < 4; ++df) {
        int row = df * 16 + l15;
        int off = (kk2 * 64 + lg * 16) ^ ((row & 7) << 4);
        vf[df] = *(const bf16x8*)((const char*)lV + row * 128 + off);
      }
#pragma unroll
      for (int m = 0; m < 2; ++m) {
        int row = m * 16 + l15;
        int off = (kk2 * 64 + lg * 16) ^ ((row & 7) << 4);
        pf[m] = *(const bf16x8*)((const char*)lP[wave] + row * 128 + off);
      }
#pragma unroll
      for (int m = 0; m < 2; ++m)
#pragma unroll
        for (int df = 0; df < 4; ++df)
          oacc[m][df] = __builtin_amdgcn_mfma_f32_16x16x32_bf16(pf[m], vf[df],
                                                                oacc[m][df], 0, 0, 0);
    }
    __syncthreads();  // protect lK/lV before next stage
  }

  // epilogue: normalize and store attnout bf16 [b*1024+r][h*64+d]
#pragma unroll
  for (int m = 0; m < 2; ++m)
#pragma unroll
    for (int j = 0; j < 4; ++j) {
      int r = qbase + m * 16 + lg * 4 + j;
      float inv = 1.0f / lrun[m][j];
#pragma unroll
      for (int df = 0; df < 4; ++df)
        attnout[((size_t)(b * 1024 + r)) * 1024 + h * 64 + df * 16 + l15] =
            f2bf(oacc[m][df][j] * inv);
    }
}

extern "C" void kernel_launch(void* const* d_in, const int* in_sizes, int n_in,
                              void* d_out, int out_size, void* d_ws, size_t ws_size,
                              hipStream_t stream) {
  const float* queries = (const float*)d_in[0];
  const float* keys1 = (const float*)d_in[1];
  const float* keys2 = (const float*)d_in[2];
  const float* values = (const float*)d_in[3];
  const float* aw = (const float*)d_in[4];
  const void* mask = d_in[5];  // bool: u8 or i32, detected in-kernel
  const float* Wq = (const float*)d_in[6];
  const float* bq = (const float*)d_in[7];
  const float* Wk1 = (const float*)d_in[8];
  const float* bk1 = (const float*)d_in[9];
  const float* Wk2 = (const float*)d_in[10];
  const float* bk2 = (const float*)d_in[11];
  const float* Wv = (const float*)d_in[12];
  const float* bv = (const float*)d_in[13];
  const float* Wo = (const float*)d_in[14];
  const float* bo = (const float*)d_in[15];

  char* ws = (char*)d_ws;
  unsigned short* qbf = (unsigned short*)(ws + (0ull << 20));
  unsigned short* khat = (unsigned short*)(ws + (8ull << 20));
  unsigned short* vTb = (unsigned short*)(ws + (16ull << 20));
  unsigned short* attno = (unsigned short*)(ws + (24ull << 20));
  unsigned short* actA = (unsigned short*)(ws + (32ull << 20));
  unsigned short* actB = (unsigned short*)(ws + (40ull << 20));
  unsigned short* WqT = (unsigned short*)(ws + (48ull << 20));
  unsigned short* Wk1T = (unsigned short*)(ws + (50ull << 20));
  unsigned short* Wk2T = (unsigned short*)(ws + (52ull << 20));
  unsigned short* WvT = (unsigned short*)(ws + (54ull << 20));
  unsigned short* WoT = (unsigned short*)(ws + (56ull << 20));

  const dim3 blk(256);
  const dim3 tg(32, 32);
  const int N4 = 1048576;  // 4*1024*1024 / 4

  transpose_bf16_kernel<<<tg, blk, 0, stream>>>(Wq, WqT, 1024, 1024);
  transpose_bf16_kernel<<<tg, blk, 0, stream>>>(Wk1, Wk1T, 1024, 1024);
  transpose_bf16_kernel<<<tg, blk, 0, stream>>>(Wk2, Wk2T, 1024, 1024);
  transpose_bf16_kernel<<<tg, blk, 0, stream>>>(Wv, WvT, 1024, 1024);
  transpose_bf16_kernel<<<tg, blk, 0, stream>>>(Wo, WoT, 1024, 1024);

  const dim3 gg(32, 8);  // M/128, N/128

  conv_bf16_kernel<<<4096, blk, 0, stream>>>(queries, actA, N4);
  gemm_kernel<<<gg, blk, 0, stream>>>(actA, WqT, nullptr, nullptr, bq, nullptr,
                                      qbf, 4096, 1024, 1024, 0);

  conv_bf16_kernel<<<4096, blk, 0, stream>>>(keys1, actA, N4);
  conv_bf16_kernel<<<4096, blk, 0, stream>>>(keys2, actB, N4);
  gemm_kernel<<<gg, blk, 0, stream>>>(actA, Wk1T, actB, Wk2T, bk1, bk2,
                                      khat, 4096, 1024, 1024, 0);

  conv_bf16_kernel<<<4096, blk, 0, stream>>>(values, actA, N4);
  gemm_kernel<<<gg, blk, 0, stream>>>(actA, WvT, nullptr, nullptr, bv, nullptr,
                                      vTb, 4096, 1024, 1024, 1);

  attn_kernel<<<512, blk, 0, stream>>>(qbf, khat, vTb, aw, mask, attno);

  gemm_kernel<<<gg, blk, 0, stream>>>(attno, WoT, nullptr, nullptr, bo, nullptr,
                                      d_out, 4096, 1024, 1024, 2);
}

// Round 3
// 327.237 us; speedup vs baseline: 1.1044x; 1.1044x over previous
//
#include <hip/hip_runtime.h>

// Dual-key attention, bf16 MFMA pipeline. ws_size >= 42 MiB.
// ws layout (MiB offsets):
//   0: qbf   [b][h][1024][64] bf16   (8 MiB)
//   8: khat  [b][h][1024][64] bf16   (8)
//  16: vT    [b][h][64][1024] bf16   (8)
//  24: attno [b*1024+n][h*64+d] bf16 (8)
//  32: WqT,Wk1T,Wk2T,WvT,WoT bf16 [N][K] (2 MiB each)

typedef short bf16x8 __attribute__((ext_vector_type(8)));
typedef float f32x4 __attribute__((ext_vector_type(4)));

__device__ __forceinline__ unsigned short f2bf(float f) {
  unsigned int u = __float_as_uint(f);
  return (unsigned short)((u + 0x7FFFu + ((u >> 16) & 1u)) >> 16);
}

__device__ __forceinline__ bf16x8 pack8(float4 a, float4 b) {
  bf16x8 r;
  r[0] = (short)f2bf(a.x); r[1] = (short)f2bf(a.y);
  r[2] = (short)f2bf(a.z); r[3] = (short)f2bf(a.w);
  r[4] = (short)f2bf(b.x); r[5] = (short)f2bf(b.y);
  r[6] = (short)f2bf(b.z); r[7] = (short)f2bf(b.w);
  return r;
}

__device__ __forceinline__ void gload_lds16(const void* g, void* l) {
  __builtin_amdgcn_global_load_lds(
      (const __attribute__((address_space(1))) unsigned int*)g,
      (__attribute__((address_space(3))) unsigned int*)l, 16, 0, 0);
}

// ---------------- batched W [1024][1024] fp32 -> W^T bf16 (5 weights) -------
struct W5 { const float *w0, *w1, *w2, *w3, *w4; };

__global__ __launch_bounds__(256) void transpose5_kernel(W5 w, unsigned short* out) {
  __shared__ float tile[32][33];
  const int z = blockIdx.z;
  const float* in = (z == 0) ? w.w0 : (z == 1) ? w.w1 : (z == 2) ? w.w2
                    : (z == 3) ? w.w3 : w.w4;
  unsigned short* o = out + (size_t)z * (1024 * 1024);
  const int x = threadIdx.x & 31;
  const int y0 = (threadIdx.x >> 5) << 2;
  const int r0 = blockIdx.y * 32, c0 = blockIdx.x * 32;
#pragma unroll
  for (int i = 0; i < 4; ++i)
    tile[y0 + i][x] = in[(size_t)(r0 + y0 + i) * 1024 + c0 + x];
  __syncthreads();
#pragma unroll
  for (int i = 0; i < 4; ++i) {
    int c = y0 + i;
    o[(size_t)(c0 + c) * 1024 + r0 + x] = f2bf(tile[x][c]);
  }
}

// ---------------- 64x64-tile MFMA GEMM: C = A1@B1^T (+ A2@B2^T) + bias ------
// AMODE 0: A fp32 (converted during reg-staging). AMODE 1: A bf16 (gload_lds).
// B: [N][K] bf16 (W^T). Double-buffered LDS, prefetch overlaps MFMA.
// omode 0: bf16 out [b][h][n][64]; 1: bf16 out [b][h][64][n]; 2: fp32 [M][N].
template <int AMODE>
__global__ __launch_bounds__(256, 4) void gemm64_kernel(
    const void* A1v, const unsigned short* __restrict__ B1,
    const void* A2v, const unsigned short* __restrict__ B2,
    const float* __restrict__ bias1, const float* __restrict__ bias2,
    void* __restrict__ outp, int M, int N, int K, int omode) {
  __shared__ unsigned short lA[2][64 * 32];
  __shared__ unsigned short lB[2][64 * 32];
  const int tid = threadIdx.x;
  const int lane = tid & 63, wave = tid >> 6;
  const int l15 = lane & 15, lg = lane >> 4;
  const int m0 = blockIdx.x * 64, n0 = blockIdx.y * 64;
  const int wr = wave >> 1, wc = wave & 1;  // 2x2 waves, 32x32 each
  const int arow = tid >> 2;                // staging row 0..63
  const int ac8 = (tid & 3) * 8;            // staging col offset (elems)

  f32x4 zero4 = {0.f, 0.f, 0.f, 0.f};
  f32x4 acc[2][2];
#pragma unroll
  for (int i = 0; i < 2; ++i)
#pragma unroll
    for (int j = 0; j < 2; ++j) acc[i][j] = zero4;

  const int ksteps = K >> 5;
  const int npair = (A2v != nullptr) ? 2 : 1;
  const int nsteps = npair * ksteps;

  // prologue: stage step 0 into buf 0
  {
    gload_lds16(&B1[(size_t)(n0 + arow) * K + ac8], (char*)lB[0] + wave * 1024);
    if (AMODE == 0) {
      const float* A = (const float*)A1v;
      float4 ax = *(const float4*)&A[(size_t)(m0 + arow) * K + ac8];
      float4 ay = *(const float4*)&A[(size_t)(m0 + arow) * K + ac8 + 4];
      *(bf16x8*)((char*)lA[0] + tid * 16) = pack8(ax, ay);
    } else {
      const unsigned short* A = (const unsigned short*)A1v;
      gload_lds16(&A[(size_t)(m0 + arow) * K + ac8], (char*)lA[0] + wave * 1024);
    }
  }
  __syncthreads();

  for (int s = 0; s < nsteps; ++s) {
    const int cur = s & 1, nxt = cur ^ 1;
    const bool hn = (s + 1 < nsteps);
    float4 ax, ay;
    if (hn) {
      const int s1 = s + 1;
      const int p1 = (s1 >= ksteps) ? 1 : 0;
      const int k1 = (s1 - p1 * ksteps) * 32;
      const unsigned short* B = p1 ? B2 : B1;
      gload_lds16(&B[(size_t)(n0 + arow) * K + k1 + ac8], (char*)lB[nxt] + wave * 1024);
      if (AMODE == 0) {
        const float* A = (const float*)(p1 ? A2v : A1v);
        ax = *(const float4*)&A[(size_t)(m0 + arow) * K + k1 + ac8];
        ay = *(const float4*)&A[(size_t)(m0 + arow) * K + k1 + ac8 + 4];
      } else {
        const unsigned short* A = (const unsigned short*)(p1 ? A2v : A1v);
        gload_lds16(&A[(size_t)(m0 + arow) * K + k1 + ac8], (char*)lA[nxt] + wave * 1024);
      }
    }
    bf16x8 af[2], bfr[2];
#pragma unroll
    for (int mf = 0; mf < 2; ++mf)
      af[mf] = *(const bf16x8*)&lA[cur][(wr * 32 + mf * 16 + l15) * 32 + lg * 8];
#pragma unroll
    for (int nf = 0; nf < 2; ++nf)
      bfr[nf] = *(const bf16x8*)&lB[cur][(wc * 32 + nf * 16 + l15) * 32 + lg * 8];
#pragma unroll
    for (int mf = 0; mf < 2; ++mf)
#pragma unroll
      for (int nf = 0; nf < 2; ++nf)
        acc[mf][nf] = __builtin_amdgcn_mfma_f32_16x16x32_bf16(af[mf], bfr[nf],
                                                              acc[mf][nf], 0, 0, 0);
    __syncthreads();  // reads of cur done; nxt DMA drained (vmcnt 0 in barrier)
    if (AMODE == 0 && hn) {
      *(bf16x8*)((char*)lA[nxt] + tid * 16) = pack8(ax, ay);
      __syncthreads();  // A writes visible before next iter reads
    }
  }

  unsigned short* outb = (unsigned short*)outp;
  float* outf = (float*)outp;
#pragma unroll
  for (int mf = 0; mf < 2; ++mf) {
#pragma unroll
    for (int nf = 0; nf < 2; ++nf) {
      int cg = n0 + wc * 32 + nf * 16 + l15;
      float badd = (bias1 ? bias1[cg] : 0.f) + (bias2 ? bias2[cg] : 0.f);
#pragma unroll
      for (int j = 0; j < 4; ++j) {
        int r = m0 + wr * 32 + mf * 16 + lg * 4 + j;
        float v = acc[mf][nf][j] + badd;
        if (omode == 2) {
          outf[(size_t)r * N + cg] = v;
        } else {
          int bb = r >> 10, nn = r & 1023;
          int hh = cg >> 6, dd = cg & 63;
          if (omode == 0)
            outb[(((size_t)bb * 16 + hh) * 1024 + nn) * 64 + dd] = f2bf(v);
          else
            outb[(((size_t)bb * 16 + hh) * 64 + dd) * 1024 + nn] = f2bf(v);
        }
      }
    }
  }
}

// ---------------- fused dual-key attention ----------------
// block = (bh, 64 q-rows); 4 waves x 16 q-rows. Double-buffered K/V tiles,
// one barrier per K-tile; staging DMA overlaps QK/softmax/PV.
__global__ __launch_bounds__(256, 4) void attn_kernel(
    const unsigned short* __restrict__ q, const unsigned short* __restrict__ kh,
    const unsigned short* __restrict__ vT, const float* __restrict__ aw,
    const void* __restrict__ msk, unsigned short* __restrict__ attnout) {
  __shared__ unsigned short lK[2][64 * 64];  // [k][d], rows XOR-swizzled
  __shared__ unsigned short lV[2][64 * 64];  // [d][k], rows XOR-swizzled
  __shared__ unsigned short lP[4][16 * 64];  // per-wave P tile, swizzled

  const int tid = threadIdx.x, lane = tid & 63, wave = tid >> 6;
  const int l15 = lane & 15, lg = lane >> 4;
  const int qt = blockIdx.x & 15;
  const int bh = blockIdx.x >> 4;
  const int b = bh >> 4, h = bh & 15;
  const int qbase = qt * 64 + wave * 16;  // local q row within (b,h)

  // mask dtype detection (wave-uniform): i32 0/1 words are always <=1
  unsigned w0 = ((const unsigned*)msk)[lane];
  const bool mbyte = (__ballot(w0 > 1u) != 0ull);
  const unsigned char* mp8 = (const unsigned char*)msk + (size_t)bh * 1048576;
  const int* mpi = (const int*)msk + (size_t)bh * 1048576;

  const unsigned short* qp = q + (size_t)bh * 65536;
  const unsigned short* kp = kh + (size_t)bh * 65536;
  const unsigned short* vp = vT + (size_t)bh * 65536;
  const float* awp = aw + (size_t)bh * 1048576;

  bf16x8 qf[2];
#pragma unroll
  for (int kk = 0; kk < 2; ++kk)
    qf[kk] = *(const bf16x8*)&qp[(qbase + l15) * 64 + kk * 32 + lg * 8];

  f32x4 zero4 = {0.f, 0.f, 0.f, 0.f};
  f32x4 oacc[4];
  float mrun[4], lrun[4];
#pragma unroll
  for (int x = 0; x < 4; ++x) {
    oacc[x] = zero4;
    mrun[x] = -1e30f;
    lrun[x] = 0.f;
  }

  const float scale = 0.08838834764831845f;  // 1/sqrt(128)

  // prologue: stage kt=0 into buf 0
#pragma unroll
  for (int rep = 0; rep < 2; ++rep) {
    int c = rep * 256 + tid;
    int row = c >> 3;
    int off = ((c & 7) * 16) ^ ((row & 7) << 4);
    gload_lds16(&kp[(size_t)row * 64 + (off >> 1)],
                (char*)lK[0] + rep * 4096 + wave * 1024);
    gload_lds16(&vp[(size_t)row * 1024 + (off >> 1)],
                (char*)lV[0] + rep * 4096 + wave * 1024);
  }
  __syncthreads();

  for (int kt = 0; kt < 16; ++kt) {
    const int cur = kt & 1, nxt = cur ^ 1;
    if (kt < 15) {
#pragma unroll
      for (int rep = 0; rep < 2; ++rep) {
        int c = rep * 256 + tid;
        int row = c >> 3;
        int off = ((c & 7) * 16) ^ ((row & 7) << 4);
        gload_lds16(&kp[(size_t)((kt + 1) * 64 + row) * 64 + (off >> 1)],
                    (char*)lK[nxt] + rep * 4096 + wave * 1024);
        gload_lds16(&vp[(size_t)row * 1024 + (kt + 1) * 64 + (off >> 1)],
                    (char*)lV[nxt] + rep * 4096 + wave * 1024);
      }
    }

    // S = Q @ K^T : 16 q-rows x 64 k-cols
    f32x4 sacc[4];
#pragma unroll
    for (int nf = 0; nf < 4; ++nf) sacc[nf] = zero4;
#pragma unroll
    for (int kk = 0; kk < 2; ++kk) {
      bf16x8 kf[4];
#pragma unroll
      for (int nf = 0; nf < 4; ++nf) {
        int row = nf * 16 + l15;
        int off = (kk * 64 + lg * 16) ^ ((row & 7) << 4);
        kf[nf] = *(const bf16x8*)((const char*)lK[cur] + row * 128 + off);
      }
#pragma unroll
      for (int nf = 0; nf < 4; ++nf)
        sacc[nf] = __builtin_amdgcn_mfma_f32_16x16x32_bf16(qf[kk], kf[nf],
                                                           sacc[nf], 0, 0, 0);
    }

    // scale * aw, mask, online softmax, P -> LDS (bf16)
    float pvv[4][4];
    float alpha[4];
#pragma unroll
    for (int j = 0; j < 4; ++j) {
      const int r = qbase + lg * 4 + j;
      const float* awrow = awp + (size_t)r * 1024 + kt * 64;
      const size_t mbase = (size_t)r * 1024 + kt * 64;
      int mvv[4];
      if (mbyte) {
#pragma unroll
        for (int nf = 0; nf < 4; ++nf) mvv[nf] = mp8[mbase + nf * 16 + l15];
      } else {
#pragma unroll
        for (int nf = 0; nf < 4; ++nf) mvv[nf] = mpi[mbase + nf * 16 + l15];
      }
      float mx = -1e30f;
#pragma unroll
      for (int nf = 0; nf < 4; ++nf) {
        int c = nf * 16 + l15;
        float s = sacc[nf][j] * scale * awrow[c];
        s = mvv[nf] ? -1e30f : s;
        pvv[j][nf] = s;
        mx = fmaxf(mx, s);
      }
      mx = fmaxf(mx, __shfl_xor(mx, 1));
      mx = fmaxf(mx, __shfl_xor(mx, 2));
      mx = fmaxf(mx, __shfl_xor(mx, 4));
      mx = fmaxf(mx, __shfl_xor(mx, 8));
      float mnew = fmaxf(mrun[j], mx);
      float al = __expf(mrun[j] - mnew);
      mrun[j] = mnew;
      float psum = 0.f;
#pragma unroll
      for (int nf = 0; nf < 4; ++nf) {
        float s = pvv[j][nf];
        float p = (s <= -1e29f) ? 0.f : __expf(s - mnew);
        pvv[j][nf] = p;
        psum += p;
      }
      psum += __shfl_xor(psum, 1);
      psum += __shfl_xor(psum, 2);
      psum += __shfl_xor(psum, 4);
      psum += __shfl_xor(psum, 8);
      lrun[j] = lrun[j] * al + psum;
      alpha[j] = al;
    }
#pragma unroll
    for (int df = 0; df < 4; ++df)
#pragma unroll
      for (int j = 0; j < 4; ++j) oacc[df][j] *= alpha[j];
#pragma unroll
    for (int j = 0; j < 4; ++j) {
      int prow = lg * 4 + j;
#pragma unroll
      for (int nf = 0; nf < 4; ++nf) {
        int pb = ((nf * 16 + l15) * 2) ^ ((prow & 7) << 4);
        *(unsigned short*)((char*)lP[wave] + prow * 128 + pb) = f2bf(pvv[j][nf]);
      }
    }

    // O += P @ V
#pragma unroll
    for (int kk2 = 0; kk2 < 2; ++kk2) {
      bf16x8 vf[4], pf;
#pragma unroll
      for (int df = 0; df < 4; ++df) {
        int row = df * 16 + l15;
        int off = (kk2 * 64 + lg * 16) ^ ((row & 7) << 4);
        vf[df] = *(const bf16x8*)((const char*)lV[cur] + row * 128 + off);
      }
      {
        int off = (kk2 * 64 + lg * 16) ^ ((l15 & 7) << 4);
        pf = *(const bf16x8*)((const char*)lP[wave] + l15 * 128 + off);
      }
#pragma unroll
      for (int df = 0; df < 4; ++df)
        oacc[df] = __builtin_amdgcn_mfma_f32_16x16x32_bf16(pf, vf[df],
                                                           oacc[df], 0, 0, 0);
    }
    __syncthreads();  // drains vmcnt: next tile staged; all reads of cur done
  }

  // epilogue: normalize, store bf16 [b*1024+r][h*64+d]
#pragma unroll
  for (int j = 0; j < 4; ++j) {
    int r = qbase + lg * 4 + j;
    float inv = 1.0f / lrun[j];
#pragma unroll
    for (int df = 0; df < 4; ++df)
      attnout[((size_t)(b * 1024 + r)) * 1024 + h * 64 + df * 16 + l15] =
          f2bf(oacc[df][j] * inv);
  }
}

extern "C" void kernel_launch(void* const* d_in, const int* in_sizes, int n_in,
                              void* d_out, int out_size, void* d_ws, size_t ws_size,
                              hipStream_t stream) {
  const float* queries = (const float*)d_in[0];
  const float* keys1 = (const float*)d_in[1];
  const float* keys2 = (const float*)d_in[2];
  const float* values = (const float*)d_in[3];
  const float* aw = (const float*)d_in[4];
  const void* mask = d_in[5];
  const float* Wq = (const float*)d_in[6];
  const float* bq = (const float*)d_in[7];
  const float* Wk1 = (const float*)d_in[8];
  const float* bk1 = (const float*)d_in[9];
  const float* Wk2 = (const float*)d_in[10];
  const float* bk2 = (const float*)d_in[11];
  const float* Wv = (const float*)d_in[12];
  const float* bv = (const float*)d_in[13];
  const float* Wo = (const float*)d_in[14];
  const float* bo = (const float*)d_in[15];

  char* ws = (char*)d_ws;
  unsigned short* qbf = (unsigned short*)(ws + (0ull << 20));
  unsigned short* khat = (unsigned short*)(ws + (8ull << 20));
  unsigned short* vTb = (unsigned short*)(ws + (16ull << 20));
  unsigned short* attno = (unsigned short*)(ws + (24ull << 20));
  unsigned short* WT = (unsigned short*)(ws + (32ull << 20));
  unsigned short* WqT = WT;
  unsigned short* Wk1T = WT + 1 * 1048576;
  unsigned short* Wk2T = WT + 2 * 1048576;
  unsigned short* WvT = WT + 3 * 1048576;
  unsigned short* WoT = WT + 4 * 1048576;

  transpose5_kernel<<<dim3(32, 32, 5), 256, 0, stream>>>(
      W5{Wq, Wk1, Wk2, Wv, Wo}, WT);

  const dim3 gg(64, 16);  // M/64, N/64
  gemm64_kernel<0><<<gg, 256, 0, stream>>>(queries, WqT, nullptr, nullptr,
                                           bq, nullptr, qbf, 4096, 1024, 1024, 0);
  gemm64_kernel<0><<<gg, 256, 0, stream>>>(keys1, Wk1T, keys2, Wk2T,
                                           bk1, bk2, khat, 4096, 1024, 1024, 0);
  gemm64_kernel<0><<<gg, 256, 0, stream>>>(values, WvT, nullptr, nullptr,
                                           bv, nullptr, vTb, 4096, 1024, 1024, 1);

  attn_kernel<<<1024, 256, 0, stream>>>(qbf, khat, vTb, aw, mask, attno);

  gemm64_kernel<1><<<gg, 256, 0, stream>>>(attno, WoT, nullptr, nullptr,
                                           bo, nullptr, d_out, 4096, 1024, 1024, 2);
}